// Round 10
// baseline (249.015 us; speedup 1.0000x reference)
//
#include <hip/hip_runtime.h>
#include <hip/hip_bf16.h>

#define M_TOTAL 16384
#define KDIM 2048
#define NDIM 2048
#define NEXP 8
#define BM 256
#define BN 256
#define BK 32
#define MAX_ROW_TILES 71  // 16384/256 + 7 boundary extras
#define NWG (MAX_ROW_TILES * 8)

typedef __attribute__((ext_vector_type(8))) __bf16 bf16x8;
typedef __attribute__((ext_vector_type(4))) float f32x4;

__device__ inline int minI(int a, int b) { return a < b ? a : b; }

__device__ inline bf16x8 cvt8(float4 a, float4 b) {
  bf16x8 r;
  r[0] = (__bf16)a.x; r[1] = (__bf16)a.y; r[2] = (__bf16)a.z; r[3] = (__bf16)a.w;
  r[4] = (__bf16)b.x; r[5] = (__bf16)b.y; r[6] = (__bf16)b.z; r[7] = (__bf16)b.w;
  return r;
}

__device__ inline void gload16(const void* g, void* l) {
  __builtin_amdgcn_global_load_lds(
      (const __attribute__((address_space(1))) void*)g,
      (__attribute__((address_space(3))) void*)l, 16, 0, 0);
}

// ---------------- fp32 -> bf16 conversion (x then W) ----------------
__global__ __launch_bounds__(256) void cvt_both(
    const float* __restrict__ x, const float* __restrict__ w,
    bf16x8* __restrict__ xb, bf16x8* __restrict__ wb) {
  const int NX = (M_TOTAL * KDIM) / 8;
  const int NW = (NEXP * NDIM * KDIM) / 8;
  const int stride = gridDim.x * blockDim.x;
  for (int i = blockIdx.x * blockDim.x + threadIdx.x; i < NX + NW; i += stride) {
    const float4* src = (i < NX) ? ((const float4*)x + (size_t)i * 2)
                                 : ((const float4*)w + (size_t)(i - NX) * 2);
    float4 a = src[0], b = src[1];
    bf16x8 c = cvt8(a, b);
    if (i < NX) xb[i] = c; else wb[i - NX] = c;
  }
}

// ---------------- grouped GEMM: 256x256, BK=32, 4 LDS buffers (128 KB),
// ONE raw barrier + ONE clobber-free counted vmcnt(4) per K-tile; NO manual
// lgkmcnt, NO asm memory clobbers, NO empty fences. The round-8 variant of
// this structure was crippled by clobbered asm: SIInsertWaitcnts treats
// memory-clobbered inline asm as may-access-memory and drains vmcnt+lgkmcnt
// to 0 before it, exposing full global latency per tile. Clobber-free, the
// counted wait survives, and with no barrier+lgkm(0) in front of the MFMA
// cluster the compiler interleaves the 12 ds_reads with the 32 MFMAs using
// fine-grained partial lgkm waits -- waves de-synchronize after the barrier
// instead of stalling on LDS latency in lockstep (the R4-R9 defect).
// Hazards: RAW -- reads(t) need buf staged at t-2; vmcnt(4) before barrier(t)
// leaves only tile t+1's 4 loads outstanding, so buf(t) is resident and the
// barrier publishes it. WAR -- stage(t+2) after barrier(t) targets the buffer
// read at t-2; those reads completed before their MFMAs, which completed
// before each wave reached barrier(t). Raw s_barrier is a compiler scheduling
// boundary for memory ops (intrinsic with side effects), so ds_reads cannot
// hoist above it. Swizzle (verified 0 conflicts R3-R9): phys chunk =
// c ^ ((row>>1)&3) via pre-swizzled per-lane global source; LDS dest linear.
__global__ __launch_bounds__(512, 2) void moe_gemm_fr(
    const __hip_bfloat16* __restrict__ xb, const __hip_bfloat16* __restrict__ wb,
    const int* __restrict__ ms, float* __restrict__ out) {
  __shared__ __align__(16) char lds[131072];

  // bijective XCD swizzle (NWG = 568 = 8*71)
  const int orig = blockIdx.x;
  const int wg = (orig & 7) * MAX_ROW_TILES + (orig >> 3);
  const int bt = wg >> 3;
  const int ntile = wg & 7;

  // ---- map bt -> (expert e, row0, rows) ----
  int sizes[NEXP];
#pragma unroll
  for (int i = 0; i < NEXP; ++i) sizes[i] = ms[i];
  int e = 0, row0 = 0, rows = 0, acc_t = 0, start = 0;
  bool found = false;
#pragma unroll
  for (int i = 0; i < NEXP; ++i) {
    int nt = (sizes[i] + BM - 1) >> 8;
    if (!found && bt < acc_t + nt) {
      found = true; e = i;
      int tt = bt - acc_t;
      row0 = start + tt * BM;
      rows = minI(sizes[i] - tt * BM, BM);
    }
    acc_t += nt; start += sizes[i];
  }
  if (!found) return;

  const int tid = threadIdx.x;
  const int lane = tid & 63;
  const int wave = tid >> 6;
  const int wr = wave >> 2, wc = wave & 3;  // 2x4 waves, 128x64 out each
  const int col0 = ntile * BN;

  // ---- staging: 4 units of 8KB per tile; thread -> row rwh = wave*16+lane>>2,
  // phys chunk lane&3; logical chunk = (lane&3)^((rwh>>1)&3) = (lane&3)^((lane>>3)&3)
  const int rwh = wave * 16 + (lane >> 2);
  const int colel = (((lane & 3) ^ ((lane >> 3) & 3)) << 3);
  const __hip_bfloat16* aS0 = xb + (size_t)minI(row0 + rwh, M_TOTAL - 1) * KDIM + colel;
  const __hip_bfloat16* aS1 = xb + (size_t)minI(row0 + 128 + rwh, M_TOTAL - 1) * KDIM + colel;
  const __hip_bfloat16* wbase = wb + (size_t)e * NDIM * KDIM;
  const __hip_bfloat16* bS0 = wbase + (size_t)(col0 + rwh) * KDIM + colel;
  const __hip_bfloat16* bS1 = wbase + (size_t)(col0 + 128 + rwh) * KDIM + colel;

  // ---- fragment read offsets (within a buffer), swizzled ----
  const int fr = lane & 15, fc = lane >> 4;
  const int laneOff = fr * 64 + ((fc ^ ((fr >> 1) & 3)) << 4);
  const int aOff = wr * 8192 + laneOff;
  const int bOff = 16384 + (wc >> 1) * 8192 + (wc & 1) * 4096 + laneOff;

  f32x4 acc[8][4];
  const f32x4 zero = {0.f, 0.f, 0.f, 0.f};
#pragma unroll
  for (int i = 0; i < 8; ++i)
#pragma unroll
    for (int j = 0; j < 4; ++j) acc[i][j] = zero;

#define ST4(BI, T) { char* b_ = lds + (BI) * 32768 + wave * 1024; \
    gload16(aS0 + (size_t)(T) * BK, b_); \
    gload16(aS1 + (size_t)(T) * BK, b_ + 8192); \
    gload16(bS0 + (size_t)(T) * BK, b_ + 16384); \
    gload16(bS1 + (size_t)(T) * BK, b_ + 24576); }
#define VM4 "vmcnt(4)"
#define VM0 "vmcnt(0)"

#define TILE(BI, T, DOST, VM) { \
    asm volatile("s_waitcnt " VM); \
    __builtin_amdgcn_s_barrier(); \
    if (DOST) ST4(((BI) + 2) & 3, (T) + 2); \
    const char* bb_ = lds + (BI) * 32768; \
    bf16x8 af[8], bv[4]; \
    bv[0] = *(const bf16x8*)(bb_ + bOff); \
    _Pragma("unroll") for (int mt = 0; mt < 8; ++mt) \
      af[mt] = *(const bf16x8*)(bb_ + aOff + mt * 1024); \
    _Pragma("unroll") for (int nt = 1; nt < 4; ++nt) \
      bv[nt] = *(const bf16x8*)(bb_ + bOff + nt * 1024); \
    __builtin_amdgcn_s_setprio(1); \
    _Pragma("unroll") for (int nt = 0; nt < 4; ++nt) \
      _Pragma("unroll") for (int mt = 0; mt < 8; ++mt) \
        acc[mt][nt] = __builtin_amdgcn_mfma_f32_16x16x32_bf16( \
            af[mt], bv[nt], acc[mt][nt], 0, 0, 0); \
    __builtin_amdgcn_s_setprio(0); \
  }

  // prologue: tiles 0,1 in flight (8 loads/thread)
  ST4(0, 0)
  ST4(1, 1)

  for (int i = 0; i < 15; ++i) {
    const int t = 4 * i;
    TILE(0, t,     true, VM4)
    TILE(1, t + 1, true, VM4)
    TILE(2, t + 2, true, VM4)
    TILE(3, t + 3, true, VM4)
  }
  TILE(0, 60, true,  VM4)
  TILE(1, 61, true,  VM4)
  TILE(2, 62, false, VM4)
  TILE(3, 63, false, VM0)

#undef TILE
#undef VM0
#undef VM4
#undef ST4

  // ---- epilogue: C/D layout col=lane&15, row=(lane>>4)*4+j ----
  const int er = (lane >> 4) * 4;
#pragma unroll
  for (int mt = 0; mt < 8; ++mt) {
#pragma unroll
    for (int j = 0; j < 4; ++j) {
      int r = wr * 128 + mt * 16 + er + j;
      if (r < rows) {
        float* op = out + (size_t)(row0 + r) * NDIM + col0 + wc * 64 + (lane & 15);
#pragma unroll
        for (int nt = 0; nt < 4; ++nt) op[nt * 16] = acc[mt][nt][j];
      }
    }
  }
}

// ---------------- fallback: direct fp32, reg-staged ----------------
__global__ __launch_bounds__(256) void moe_gemm_f32(
    const float* __restrict__ x, const float* __restrict__ w,
    const int* __restrict__ ms, float* __restrict__ out) {
  __shared__ __align__(16) char As[128 * 64 * 2];
  __shared__ __align__(16) char Bs[128 * 64 * 2];
  int sizes[NEXP];
#pragma unroll
  for (int i = 0; i < NEXP; ++i) sizes[i] = ms[i];
  const int bt = blockIdx.y;
  int e = 0, row0 = 0, rows = 0, acc_t = 0, start = 0;
  bool found = false;
#pragma unroll
  for (int i = 0; i < NEXP; ++i) {
    int nt = (sizes[i] + 127) >> 7;
    if (!found && bt < acc_t + nt) {
      found = true; e = i;
      int tt = bt - acc_t;
      row0 = start + tt * 128;
      rows = minI(sizes[i] - tt * 128, 128);
    }
    acc_t += nt; start += sizes[i];
  }
  if (!found) return;
  const int tid = threadIdx.x;
  const int lane = tid & 63;
  const int wave = tid >> 6;
  const int wm = wave >> 1, wn = wave & 1;
  const int col0 = blockIdx.x * 128;
  const float* wbase = w + (size_t)e * (size_t)NDIM * KDIM;
  const int sr = tid >> 1;
  const int sh = tid & 1;
  const float* aptr = x + (size_t)(row0 + sr) * KDIM + sh * 32;
  const float* bptr = wbase + (size_t)(col0 + sr) * KDIM + sh * 32;
  const bool aval = (sr < rows);
  f32x4 acc[4][4];
  const f32x4 zero = {0.f, 0.f, 0.f, 0.f};
#pragma unroll
  for (int i = 0; i < 4; ++i)
#pragma unroll
    for (int j = 0; j < 4; ++j) acc[i][j] = zero;
  for (int kb = 0; kb < KDIM / 64; ++kb) {
    {
      float4 v[8];
      if (aval) {
        const float4* p = (const float4*)(aptr + kb * 64);
#pragma unroll
        for (int j = 0; j < 8; ++j) v[j] = p[j];
      } else {
#pragma unroll
        for (int j = 0; j < 8; ++j) v[j] = make_float4(0.f, 0.f, 0.f, 0.f);
      }
#pragma unroll
      for (int j = 0; j < 4; ++j) {
        bf16x8 c = cvt8(v[2 * j], v[2 * j + 1]);
        int chunk = (sh * 4 + j) ^ (sr & 7);
        *(bf16x8*)(As + sr * 128 + chunk * 16) = c;
      }
    }
    {
      const float4* p = (const float4*)(bptr + kb * 64);
      float4 u[8];
#pragma unroll
      for (int j = 0; j < 8; ++j) u[j] = p[j];
#pragma unroll
      for (int j = 0; j < 4; ++j) {
        bf16x8 c = cvt8(u[2 * j], u[2 * j + 1]);
        int chunk = (sh * 4 + j) ^ (sr & 7);
        *(bf16x8*)(Bs + sr * 128 + chunk * 16) = c;
      }
    }
    __syncthreads();
#pragma unroll
    for (int ks = 0; ks < 2; ++ks) {
      bf16x8 afr[4], bfv[4];
#pragma unroll
      for (int mt = 0; mt < 4; ++mt) {
        int r = wm * 64 + mt * 16 + (lane & 15);
        int chunk = (ks * 4 + (lane >> 4)) ^ (r & 7);
        afr[mt] = *(const bf16x8*)(As + r * 128 + chunk * 16);
      }
#pragma unroll
      for (int nt = 0; nt < 4; ++nt) {
        int r = wn * 64 + nt * 16 + (lane & 15);
        int chunk = (ks * 4 + (lane >> 4)) ^ (r & 7);
        bfv[nt] = *(const bf16x8*)(Bs + r * 128 + chunk * 16);
      }
#pragma unroll
      for (int mt = 0; mt < 4; ++mt)
#pragma unroll
        for (int nt = 0; nt < 4; ++nt)
          acc[mt][nt] = __builtin_amdgcn_mfma_f32_16x16x32_bf16(
              afr[mt], bfv[nt], acc[mt][nt], 0, 0, 0);
    }
    __syncthreads();
  }
#pragma unroll
  for (int mt = 0; mt < 4; ++mt) {
#pragma unroll
    for (int j = 0; j < 4; ++j) {
      int r = wm * 64 + mt * 16 + (lane >> 4) * 4 + j;
      if (r < rows) {
        float* op = out + (size_t)(row0 + r) * NDIM + col0 + wn * 64 + (lane & 15);
#pragma unroll
        for (int nt = 0; nt < 4; ++nt) op[nt * 16] = acc[mt][nt][j];
      }
    }
  }
}

extern "C" void kernel_launch(void* const* d_in, const int* in_sizes, int n_in,
                              void* d_out, int out_size, void* d_ws, size_t ws_size,
                              hipStream_t stream) {
  const float* x = (const float*)d_in[0];
  const float* w = (const float*)d_in[1];
  const int* ms = (const int*)d_in[2];
  float* out = (float*)d_out;
  const size_t nx = (size_t)M_TOTAL * KDIM;
  const size_t nw = (size_t)NEXP * NDIM * KDIM;
  const size_t need = (nx + nw) * sizeof(__hip_bfloat16);
  if (ws_size >= need) {
    __hip_bfloat16* xb = (__hip_bfloat16*)d_ws;
    __hip_bfloat16* wb = xb + nx;
    cvt_both<<<2048, 256, 0, stream>>>(x, w, (bf16x8*)xb, (bf16x8*)wb);
    moe_gemm_fr<<<dim3(NWG), dim3(512), 0, stream>>>(xb, wb, ms, out);
  } else {
    moe_gemm_f32<<<dim3(16, 135), dim3(256), 0, stream>>>(x, w, ms, out);
  }
}